// Round 6
// baseline (297.304 us; speedup 1.0000x reference)
//
#include <hip/hip_runtime.h>
#include <math.h>

#define DIM   2048
#define NREF  30
#define KPAD  32
#define BATCH 16384

typedef __attribute__((ext_vector_type(8))) short short8;
typedef __attribute__((ext_vector_type(4))) float f32x4;
typedef __attribute__((ext_vector_type(2))) float f32x2;

typedef const __attribute__((address_space(1))) void* gas1_t;
typedef __attribute__((address_space(3))) void* las3_t;

// Workspace float offsets
#define WS_VN   0         // 30*2048 fp32
#define WS_G    61440     // 1024
#define WS_T    62464     // 1024
#define WS_FP1  63488     // bf16 B-frags of W2: [64 kstep][2 ntile][64 lane][8]  (128 KB)
#define WS_S    96256     // fp32 S [16384][32]  (2 MB)

__device__ __forceinline__ unsigned short f2bf(float f) {
    unsigned u = __float_as_uint(f);
    u += 0x7FFF + ((u >> 16) & 1);          // round-to-nearest-even
    return (unsigned short)(u >> 16);
}

// ---- prep: blocks 0..29 normalize rows; blocks 30..929 compute G from raw vec ----
__global__ void k_prep(const float* __restrict__ vec, float* __restrict__ vn,
                       float* __restrict__ G) {
    int b = blockIdx.x, t = threadIdx.x;
    __shared__ float wsum[3][4];
    if (b < NREF) {
        const float* v = vec + b * DIM;
        float s = 0.f;
        for (int d = t; d < DIM; d += 256) { float xv = v[d]; s += xv * xv; }
        #pragma unroll
        for (int off = 32; off > 0; off >>= 1) s += __shfl_down(s, off);
        if ((t & 63) == 0) wsum[0][t >> 6] = s;
        __syncthreads();
        float tot = wsum[0][0] + wsum[0][1] + wsum[0][2] + wsum[0][3];
        float scale = 1.f / (sqrtf(tot) + 1e-8f);
        float* o = vn + b * DIM;
        for (int d = t; d < DIM; d += 256) o[d] = v[d] * scale;
    } else {
        int idx = b - NREF;
        int i = idx / NREF, j = idx % NREF;
        const float* a = vec + i * DIM;
        const float* c = vec + j * DIM;
        float sab = 0.f, saa = 0.f, sbb = 0.f;
        for (int d = t; d < DIM; d += 256) {
            float av = a[d], cv = c[d];
            sab += av * cv; saa += av * av; sbb += cv * cv;
        }
        #pragma unroll
        for (int off = 32; off > 0; off >>= 1) {
            sab += __shfl_down(sab, off);
            saa += __shfl_down(saa, off);
            sbb += __shfl_down(sbb, off);
        }
        if ((t & 63) == 0) { wsum[0][t >> 6] = sab; wsum[1][t >> 6] = saa; wsum[2][t >> 6] = sbb; }
        __syncthreads();
        if (t == 0) {
            float tab = wsum[0][0] + wsum[0][1] + wsum[0][2] + wsum[0][3];
            float taa = wsum[1][0] + wsum[1][1] + wsum[1][2] + wsum[1][3];
            float tbb = wsum[2][0] + wsum[2][1] + wsum[2][2] + wsum[2][3];
            G[i * NREF + j] = tab / ((sqrtf(taa) + 1e-8f) * (sqrtf(tbb) + 1e-8f));
        }
    }
}

// ---- T: per-ROW recurrence, G cached in LDS, zero cross-thread deps ----
__global__ void k_T2(const float* __restrict__ G, float* __restrict__ T) {
    int t = threadIdx.x;  // 64 threads
    __shared__ float Gs[NREF * NREF];
    __shared__ float Ts[NREF][NREF];
    for (int idx = t; idx < NREF * NREF; idx += 64) {
        Gs[idx] = G[idx];
        Ts[idx / NREF][idx % NREF] = 0.f;
    }
    __syncthreads();
    if (t < NREF) {
        Ts[t][t] = 2.f;
        for (int j = t + 1; j < NREF; j++) {
            float val = 0.f;
            for (int mm = t; mm < j; mm++) val += Ts[t][mm] * Gs[mm * NREF + j];
            Ts[t][j] = -2.f * val;
        }
    }
    __syncthreads();
    for (int idx = t; idx < NREF * NREF; idx += 64) T[idx] = Ts[idx / NREF][idx % NREF];
}

// ---- mid: W2 (in LDS) + pack1 for the phase-1 MFMA B operand ----
__global__ void k_mid(const float* __restrict__ vn, const float* __restrict__ T,
                      unsigned short* __restrict__ fp1) {
    int b = blockIdx.x, t = threadIdx.x;
    __shared__ float W2s[256][33];
    int d = b * 256 + t;
    float vr[NREF];
    #pragma unroll
    for (int j = 0; j < NREF; j++) vr[j] = vn[j * DIM + d];
    #pragma unroll
    for (int k = 0; k < KPAD; k++) {
        float acc = 0.f;
        if (k < NREF)
            for (int j = 0; j <= k; j++) acc += vr[j] * T[j * NREF + k];
        W2s[t][k] = acc;
    }
    __syncthreads();
    short8* out = (short8*)fp1;
    #pragma unroll
    for (int u = 0; u < 4; u++) {
        int lf = t * 4 + u;
        int ks_l = lf >> 7, nt = (lf >> 6) & 1, lane = lf & 63;
        int q = lane >> 4, n = lane & 15;
        short8 v;
        #pragma unroll
        for (int j = 0; j < 8; j++)
            v[j] = (short)f2bf(W2s[ks_l * 32 + q * 8 + j][nt * 16 + n]);
        out[((b * 8 + ks_l) * 2 + nt) * 64 + lane] = v;
    }
}

// ---- phase 1: S = x*W2 via MFMA with CONTIGUOUS DMA staging of x ----
// Evidence r1-r5: MFMA-A-layout direct x loads (16 rows 8KB apart per instr, 64
// scattered 16B requests, no inter-lane coalescing) cap at 2-3 TB/s; contiguous
// streams hit ~6.3. Fix: double-buffered 16x256 LDS chunks staged by
// global_load_lds with per-instruction-contiguous 1KB sources; fp1 B-frags
// prefetched one chunk ahead into REGISTERS so the compute phase issues ZERO
// VMEM -> the counted vmcnt(8) (4 fp1-prefetch + 4 stage DMAs younger, in-order
// per wave) never drains the DMA pipeline. Raw s_barrier (no compiler vmcnt(0)).
// 3 blocks/CU x 16KB stages keeps ~48KB/CU in flight (need ~9KB for 6 TB/s).
__global__ __launch_bounds__(256) void k_p1(const float* __restrict__ x,
                                            const short8* __restrict__ fp1,
                                            float* __restrict__ S) {
    __shared__ float xs[2][16][260];         // 33.3 KB, pad 260 -> bank-spread reads
    __shared__ f32x4 red[4][64][2];          // 8 KB
    int tid = threadIdx.x;
    int wave = tid >> 6, lane = tid & 63;
    int m = lane & 15, q = lane >> 4;
    int r0 = blockIdx.x * 16;

    const char* xbase = (const char*)(x + (size_t)r0 * DIM);

    // stage chunk c (cols c*256..+255) into buffer b; wave stages rows 4w..4w+3,
    // one contiguous 1KB instruction per row (dest = row base + lane*16, linear)
    auto STAGE = [&](int c, int b) {
        #pragma unroll
        for (int i = 0; i < 4; i++) {
            int r = wave * 4 + i;
            const char* g = xbase + (size_t)r * (DIM * 4) + c * 1024 + (size_t)(lane * 16);
            __builtin_amdgcn_global_load_lds((gas1_t)g, (las3_t)((char*)&xs[b][r][0]),
                                             16, 0, 0);
        }
    };

    // fp1 frag prefetch: wave w owns ksteps {2w, 2w+1} of each chunk
    short8 f0a, f0b, f1a, f1b, n0a, n0b, n1a, n1b;
    {
        int ksg = wave * 2;
        f0a = fp1[(ksg * 2 + 0) * 64 + lane];
        f0b = fp1[(ksg * 2 + 1) * 64 + lane];
        f1a = fp1[((ksg + 1) * 2 + 0) * 64 + lane];
        f1b = fp1[((ksg + 1) * 2 + 1) * 64 + lane];
    }
    STAGE(0, 0);

    f32x4 acc0 = {0.f, 0.f, 0.f, 0.f};
    f32x4 acc1 = {0.f, 0.f, 0.f, 0.f};

    #pragma unroll
    for (int c = 0; c < 8; c++) {
        int b = c & 1;
        if (c < 7) {
            int ksg = (c + 1) * 8 + wave * 2;
            n0a = fp1[(ksg * 2 + 0) * 64 + lane];
            n0b = fp1[(ksg * 2 + 1) * 64 + lane];
            n1a = fp1[((ksg + 1) * 2 + 0) * 64 + lane];
            n1b = fp1[((ksg + 1) * 2 + 1) * 64 + lane];
            STAGE(c + 1, b ^ 1);
            asm volatile("s_waitcnt vmcnt(8)" ::: "memory");   // stage(c)+fp1(c) done
        } else {
            asm volatile("s_waitcnt vmcnt(0)" ::: "memory");
        }
        __builtin_amdgcn_s_barrier();
        __builtin_amdgcn_sched_barrier(0);

        // compute: 2 ksteps, zero VMEM (xs from LDS, fp1 from regs)
        const char* rb = (const char*)xs + b * 16640 + m * 1040 + q * 32;
        {
            f32x4 xa = *(const f32x4*)(rb + (wave * 2 + 0) * 128);
            f32x4 xb = *(const f32x4*)(rb + (wave * 2 + 0) * 128 + 16);
            short8 a;
            a[0] = (short)f2bf(xa[0]); a[1] = (short)f2bf(xa[1]);
            a[2] = (short)f2bf(xa[2]); a[3] = (short)f2bf(xa[3]);
            a[4] = (short)f2bf(xb[0]); a[5] = (short)f2bf(xb[1]);
            a[6] = (short)f2bf(xb[2]); a[7] = (short)f2bf(xb[3]);
            acc0 = __builtin_amdgcn_mfma_f32_16x16x32_bf16(a, f0a, acc0, 0, 0, 0);
            acc1 = __builtin_amdgcn_mfma_f32_16x16x32_bf16(a, f0b, acc1, 0, 0, 0);
        }
        {
            f32x4 xa = *(const f32x4*)(rb + (wave * 2 + 1) * 128);
            f32x4 xb = *(const f32x4*)(rb + (wave * 2 + 1) * 128 + 16);
            short8 a;
            a[0] = (short)f2bf(xa[0]); a[1] = (short)f2bf(xa[1]);
            a[2] = (short)f2bf(xa[2]); a[3] = (short)f2bf(xa[3]);
            a[4] = (short)f2bf(xb[0]); a[5] = (short)f2bf(xb[1]);
            a[6] = (short)f2bf(xb[2]); a[7] = (short)f2bf(xb[3]);
            acc0 = __builtin_amdgcn_mfma_f32_16x16x32_bf16(a, f1a, acc0, 0, 0, 0);
            acc1 = __builtin_amdgcn_mfma_f32_16x16x32_bf16(a, f1b, acc1, 0, 0, 0);
        }
        __builtin_amdgcn_sched_barrier(0);
        __builtin_amdgcn_s_barrier();    // all waves done reading xs[b] before restage
        f0a = n0a; f0b = n0b; f1a = n1a; f1b = n1b;
    }

    // cross-wave K reduction in LDS, fp32 S out (2 MB total)
    red[wave][lane][0] = acc0;
    red[wave][lane][1] = acc1;
    __syncthreads();
    if (tid < 64) {
        f32x4 s0 = red[0][tid][0], s1 = red[0][tid][1];
        #pragma unroll
        for (int w = 1; w < 4; w++) { s0 += red[w][tid][0]; s1 += red[w][tid][1]; }
        int mq = tid & 15, qq = tid >> 4;
        #pragma unroll
        for (int reg = 0; reg < 4; reg++) {
            size_t row = r0 + qq * 4 + reg;
            S[row * KPAD + mq]      = s0[reg];
            S[row * KPAD + 16 + mq] = s1[reg];
        }
    }
}

// ---- phase 2: y = x + bias - S*vn, pure VALU stream (unchanged, passed r5) ----
__global__ __launch_bounds__(256) void k_p2(const float* __restrict__ x,
                                            const float* __restrict__ S,
                                            const float* __restrict__ vn,
                                            const float* __restrict__ bias,
                                            float* __restrict__ y) {
    __shared__ float Stile[32 * KPAD];   // 4 KB
    int tid = threadIdx.x;
    int wave = tid >> 6, lane = tid & 63;
    int rc = blockIdx.x >> 2;            // 512 row-chunks of 32 rows
    int cg = blockIdx.x & 3;             // 4 col-groups of 512
    int r0 = rc * 32;
    int cl = cg * 512 + wave * 128 + lane * 2;

    ((f32x4*)Stile)[tid] = ((const f32x4*)(S + (size_t)r0 * KPAD))[tid];

    f32x2 vt[NREF];
    #pragma unroll
    for (int n = 0; n < NREF; n++)
        vt[n] = *(const f32x2*)(vn + n * DIM + cl);
    f32x2 bi = *(const f32x2*)(bias + cl);
    __syncthreads();

    const float* xp = x + (size_t)r0 * DIM + cl;
    float* yp = y + (size_t)r0 * DIM + cl;
    #pragma unroll 4
    for (int r = 0; r < 32; r++) {
        f32x2 xv = *(const f32x2*)(xp + (size_t)r * DIM);
        f32x2 acc = xv + bi;
        const float* Sr = &Stile[r * KPAD];
        #pragma unroll
        for (int n = 0; n < NREF; n++) {
            float sn = Sr[n];                 // wave-uniform -> LDS broadcast
            acc -= sn * vt[n];                // contracts to fma (neg modifier)
        }
        *(f32x2*)(yp + (size_t)r * DIM) = acc;
    }
}

extern "C" void kernel_launch(void* const* d_in, const int* in_sizes, int n_in,
                              void* d_out, int out_size, void* d_ws, size_t ws_size,
                              hipStream_t stream) {
    const float* x    = (const float*)d_in[0];
    const float* vec  = (const float*)d_in[1];
    const float* bias = (const float*)d_in[2];
    float* out = (float*)d_out;
    float* ws  = (float*)d_ws;

    float* vn = ws + WS_VN;
    float* G  = ws + WS_G;
    float* T  = ws + WS_T;
    unsigned short* fp1 = (unsigned short*)(ws + WS_FP1);
    float* S = ws + WS_S;

    k_prep<<<NREF + NREF * NREF, 256, 0, stream>>>(vec, vn, G);
    k_T2<<<1, 64, 0, stream>>>(G, T);
    k_mid<<<8, 256, 0, stream>>>(vn, T, fp1);
    k_p1<<<BATCH / 16, 256, 0, stream>>>(x, (const short8*)fp1, S);
    k_p2<<<2048, 256, 0, stream>>>(x, S, vn, bias, out);
}

// Round 8
// 288.416 us; speedup vs baseline: 1.0308x; 1.0308x over previous
//
#include <hip/hip_runtime.h>
#include <math.h>

#define DIM   2048
#define NREF  30
#define KPAD  32
#define BATCH 16384

typedef __attribute__((ext_vector_type(8))) short short8;
typedef __attribute__((ext_vector_type(4))) float f32x4;
typedef __attribute__((ext_vector_type(2))) float f32x2;

// Workspace float offsets
#define WS_VN   0         // 30*2048 fp32
#define WS_G    61440     // 1024
#define WS_T    62464     // 1024
#define WS_FP1  63488     // bf16 B-frags of W2: [64 kstep][2 ntile][64 lane][8]  (128 KB)

__device__ __forceinline__ unsigned short f2bf(float f) {
    unsigned u = __float_as_uint(f);
    u += 0x7FFF + ((u >> 16) & 1);          // round-to-nearest-even
    return (unsigned short)(u >> 16);
}

// ---- prep: blocks 0..29 normalize rows; blocks 30..929 compute G from raw vec ----
__global__ void k_prep(const float* __restrict__ vec, float* __restrict__ vn,
                       float* __restrict__ G) {
    int b = blockIdx.x, t = threadIdx.x;
    __shared__ float wsum[3][4];
    if (b < NREF) {
        const float* v = vec + b * DIM;
        float s = 0.f;
        for (int d = t; d < DIM; d += 256) { float xv = v[d]; s += xv * xv; }
        #pragma unroll
        for (int off = 32; off > 0; off >>= 1) s += __shfl_down(s, off);
        if ((t & 63) == 0) wsum[0][t >> 6] = s;
        __syncthreads();
        float tot = wsum[0][0] + wsum[0][1] + wsum[0][2] + wsum[0][3];
        float scale = 1.f / (sqrtf(tot) + 1e-8f);
        float* o = vn + b * DIM;
        for (int d = t; d < DIM; d += 256) o[d] = v[d] * scale;
    } else {
        int idx = b - NREF;
        int i = idx / NREF, j = idx % NREF;
        const float* a = vec + i * DIM;
        const float* c = vec + j * DIM;
        float sab = 0.f, saa = 0.f, sbb = 0.f;
        for (int d = t; d < DIM; d += 256) {
            float av = a[d], cv = c[d];
            sab += av * cv; saa += av * av; sbb += cv * cv;
        }
        #pragma unroll
        for (int off = 32; off > 0; off >>= 1) {
            sab += __shfl_down(sab, off);
            saa += __shfl_down(saa, off);
            sbb += __shfl_down(sbb, off);
        }
        if ((t & 63) == 0) { wsum[0][t >> 6] = sab; wsum[1][t >> 6] = saa; wsum[2][t >> 6] = sbb; }
        __syncthreads();
        if (t == 0) {
            float tab = wsum[0][0] + wsum[0][1] + wsum[0][2] + wsum[0][3];
            float taa = wsum[1][0] + wsum[1][1] + wsum[1][2] + wsum[1][3];
            float tbb = wsum[2][0] + wsum[2][1] + wsum[2][2] + wsum[2][3];
            G[i * NREF + j] = tab / ((sqrtf(taa) + 1e-8f) * (sqrtf(tbb) + 1e-8f));
        }
    }
}

// ---- T: per-ROW recurrence, G cached in LDS, zero cross-thread deps ----
__global__ void k_T2(const float* __restrict__ G, float* __restrict__ T) {
    int t = threadIdx.x;  // 64 threads
    __shared__ float Gs[NREF * NREF];
    __shared__ float Ts[NREF][NREF];
    for (int idx = t; idx < NREF * NREF; idx += 64) {
        Gs[idx] = G[idx];
        Ts[idx / NREF][idx % NREF] = 0.f;
    }
    __syncthreads();
    if (t < NREF) {
        Ts[t][t] = 2.f;
        for (int j = t + 1; j < NREF; j++) {
            float val = 0.f;
            for (int mm = t; mm < j; mm++) val += Ts[t][mm] * Gs[mm * NREF + j];
            Ts[t][j] = -2.f * val;
        }
    }
    __syncthreads();
    for (int idx = t; idx < NREF * NREF; idx += 64) T[idx] = Ts[idx / NREF][idx % NREF];
}

// ---- mid: W2 (in LDS) + pack1 for the phase-A MFMA B operand ----
__global__ void k_mid(const float* __restrict__ vn, const float* __restrict__ T,
                      unsigned short* __restrict__ fp1) {
    int b = blockIdx.x, t = threadIdx.x;
    __shared__ float W2s[256][33];
    int d = b * 256 + t;
    float vr[NREF];
    #pragma unroll
    for (int j = 0; j < NREF; j++) vr[j] = vn[j * DIM + d];
    #pragma unroll
    for (int k = 0; k < KPAD; k++) {
        float acc = 0.f;
        if (k < NREF)
            for (int j = 0; j <= k; j++) acc += vr[j] * T[j * NREF + k];
        W2s[t][k] = acc;
    }
    __syncthreads();
    short8* out = (short8*)fp1;
    #pragma unroll
    for (int u = 0; u < 4; u++) {
        int lf = t * 4 + u;
        int ks_l = lf >> 7, nt = (lf >> 6) & 1, lane = lf & 63;
        int q = lane >> 4, n = lane & 15;
        short8 v;
        #pragma unroll
        for (int j = 0; j < 8; j++)
            v[j] = (short)f2bf(W2s[ks_l * 32 + q * 8 + j][nt * 16 + n]);
        out[((b * 8 + ks_l) * 2 + nt) * 64 + lane] = v;
    }
}

// ---- fused per-block (NO grid sync): block owns 16 rows.
// Phase A: S = x*W2 via MFMA (r5's passing k_p1), S-tile stays in 2 KB LDS fp32.
// Phase B: y = x + bias - S*vn as a pure VALU stream (r5's passing k_p2 shape):
// lane-contiguous f32x2 loads/stores, S broadcast from LDS, vn pinned in VGPRs,
// nontemporal y stores (y never re-read; keeps L3 for x). x re-read in phase B
// is same-block L2-hot (this block fetched exactly these 128 KB in phase A).
// r7 lesson: hipLaunchCooperativeKernel silently fails under the harness's graph
// capture (absmax = max|ref|, output never written) -- per-block fusion only.
__global__ __launch_bounds__(256, 4) void k_fused(const float* __restrict__ x,
                                                  const short8* __restrict__ fp1,
                                                  const float* __restrict__ vn,
                                                  const float* __restrict__ bias,
                                                  float* __restrict__ y) {
    __shared__ f32x4 red[4][64][2];          // 8 KB
    __shared__ float Sf[16][KPAD];           // 2 KB fp32 S-tile
    int tid = threadIdx.x;
    int wave = tid >> 6, lane = tid & 63;
    int m = lane & 15, q = lane >> 4;
    int r0 = blockIdx.x * 16;

    // ================= phase A: S = x * W2 =================
    {
        int kb = wave * 512;
        const float* xp = x + (size_t)(r0 + m) * DIM + kb + q * 8;

        f32x4 acc0 = {0.f, 0.f, 0.f, 0.f};
        f32x4 acc1 = {0.f, 0.f, 0.f, 0.f};
        #pragma unroll 4
        for (int ks = 0; ks < 16; ks++) {
            f32x4 xa = *(const f32x4*)(xp + ks * 32);
            f32x4 xb = *(const f32x4*)(xp + ks * 32 + 4);
            short8 a;
            a[0] = (short)f2bf(xa[0]); a[1] = (short)f2bf(xa[1]);
            a[2] = (short)f2bf(xa[2]); a[3] = (short)f2bf(xa[3]);
            a[4] = (short)f2bf(xb[0]); a[5] = (short)f2bf(xb[1]);
            a[6] = (short)f2bf(xb[2]); a[7] = (short)f2bf(xb[3]);
            int ksg = wave * 16 + ks;
            short8 b0 = fp1[(ksg * 2 + 0) * 64 + lane];
            short8 b1 = fp1[(ksg * 2 + 1) * 64 + lane];
            acc0 = __builtin_amdgcn_mfma_f32_16x16x32_bf16(a, b0, acc0, 0, 0, 0);
            acc1 = __builtin_amdgcn_mfma_f32_16x16x32_bf16(a, b1, acc1, 0, 0, 0);
        }

        red[wave][lane][0] = acc0;
        red[wave][lane][1] = acc1;
        __syncthreads();
        if (tid < 64) {
            f32x4 s0 = red[0][tid][0], s1 = red[0][tid][1];
            #pragma unroll
            for (int w = 1; w < 4; w++) { s0 += red[w][tid][0]; s1 += red[w][tid][1]; }
            int mq = tid & 15, qq = tid >> 4;
            #pragma unroll
            for (int reg = 0; reg < 4; reg++) {
                Sf[qq * 4 + reg][mq]      = s0[reg];
                Sf[qq * 4 + reg][16 + mq] = s1[reg];
            }
        }
        __syncthreads();
    }

    // ================= phase B: y = x + bias - S * vn =================
    const float* xr = x + (size_t)r0 * DIM;
    float* yr = y + (size_t)r0 * DIM;

    #pragma unroll 1
    for (int pass = 0; pass < 4; pass++) {
        int cl = pass * 512 + tid * 2;       // lane-contiguous col pair
        f32x2 vt[32];
        #pragma unroll
        for (int n = 0; n < NREF; n++)
            vt[n] = *(const f32x2*)(vn + n * DIM + cl);
        vt[30] = (f32x2){0.f, 0.f};
        vt[31] = (f32x2){0.f, 0.f};
        f32x2 bi = *(const f32x2*)(bias + cl);

        #pragma unroll 4
        for (int r = 0; r < 16; r++) {
            f32x2 xv = *(const f32x2*)(xr + (size_t)r * DIM + cl);
            f32x2 acc = xv + bi;
            const float* Sr = &Sf[r][0];
            #pragma unroll
            for (int n4 = 0; n4 < 8; n4++) {          // b128 broadcast S reads
                f32x4 s4 = *(const f32x4*)&Sr[n4 * 4];
                acc -= s4[0] * vt[n4 * 4 + 0];
                acc -= s4[1] * vt[n4 * 4 + 1];
                acc -= s4[2] * vt[n4 * 4 + 2];
                acc -= s4[3] * vt[n4 * 4 + 3];        // S[:,30..31]==0 -> safe
            }
            __builtin_nontemporal_store(acc, (f32x2*)(yr + (size_t)r * DIM + cl));
        }
    }
}

extern "C" void kernel_launch(void* const* d_in, const int* in_sizes, int n_in,
                              void* d_out, int out_size, void* d_ws, size_t ws_size,
                              hipStream_t stream) {
    const float* x    = (const float*)d_in[0];
    const float* vec  = (const float*)d_in[1];
    const float* bias = (const float*)d_in[2];
    float* out = (float*)d_out;
    float* ws  = (float*)d_ws;

    float* vn = ws + WS_VN;
    float* G  = ws + WS_G;
    float* T  = ws + WS_T;
    unsigned short* fp1 = (unsigned short*)(ws + WS_FP1);

    k_prep<<<NREF + NREF * NREF, 256, 0, stream>>>(vec, vn, G);
    k_T2<<<1, 64, 0, stream>>>(G, T);
    k_mid<<<8, 256, 0, stream>>>(vn, T, fp1);
    k_fused<<<BATCH / 16, 256, 0, stream>>>(x, (const short8*)fp1, vn, bias, out);
}